// Round 3
// baseline (2645.290 us; speedup 1.0000x reference)
//
#include <hip/hip_runtime.h>
#include <math.h>

#define HMM_B 32
#define HMM_T 8192
#define HMM_K 64

typedef float f2 __attribute__((ext_vector_type(2)));

#define LN2F 0.69314718055994531f
#define INV_LN2F 1.4426950408889634f
#define HALF_INV_LN2_SQRTF 0.8493218002880191f  /* sqrt(0.5/ln2) */
#define NEG_HALF_LOG_2PI 0.91893853320467274f

// broadcast lane 0's value (uniform scalar via SGPR)
__device__ __forceinline__ float bcast0(float v) {
    return __int_as_float(__builtin_amdgcn_readfirstlane(__float_as_int(v)));
}
// raw transcendentals (base-2)
__device__ __forceinline__ float exp2_fast(float x) {
    float r; asm("v_exp_f32 %0, %1" : "=v"(r) : "v"(x)); return r;
}
__device__ __forceinline__ float log2_fast(float x) {
    float r; asm("v_log_f32 %0, %1" : "=v"(r) : "v"(x)); return r;
}

// one DPP-max step: max(v, lanes shifted per ctrl); pure VALU (no DS queue traffic)
template <int CTRL, int RMASK>
__device__ __forceinline__ float dpp_max(float v) {
    int s = __float_as_int(v);
    int d = __builtin_amdgcn_update_dpp(s, s, CTRL, RMASK, 0xF, false);
    return fmaxf(v, __int_as_float(d));
}
// wave64 max -> uniform SGPR value (AMD GCN crosslane reduction pattern)
__device__ __forceinline__ float wave_max_uniform(float v) {
    v = dpp_max<0x111, 0xF>(v);   // row_shr:1
    v = dpp_max<0x112, 0xF>(v);   // row_shr:2
    v = dpp_max<0x114, 0xF>(v);   // row_shr:4
    v = dpp_max<0x118, 0xF>(v);   // row_shr:8
    v = dpp_max<0x142, 0xA>(v);   // row_bcast:15 -> rows 1,3
    v = dpp_max<0x143, 0xC>(v);   // row_bcast:31 -> rows 2,3
    return __int_as_float(__builtin_amdgcn_readlane(__float_as_int(v), 63));
}

// u_i = sum_j A[i][j]*w[j]; A register-resident as float2 pairs -> v_pk_fma_f32
__device__ __forceinline__ float matvec_row(const f2* __restrict__ areg,
                                            const float4* __restrict__ wv) {
    f2 a0 = {0.f, 0.f}, a1 = {0.f, 0.f}, a2 = {0.f, 0.f}, a3 = {0.f, 0.f};
    #pragma unroll
    for (int j = 0; j < 8; ++j) {
        float4 wA = wv[2 * j];
        float4 wB = wv[2 * j + 1];
        f2 wa01; wa01.x = wA.x; wa01.y = wA.y;
        f2 wa23; wa23.x = wA.z; wa23.y = wA.w;
        f2 wb01; wb01.x = wB.x; wb01.y = wB.y;
        f2 wb23; wb23.x = wB.z; wb23.y = wB.w;
        a0 += areg[4 * j + 0] * wa01;
        a1 += areg[4 * j + 1] * wa23;
        a2 += areg[4 * j + 2] * wb01;
        a3 += areg[4 * j + 3] * wb23;
    }
    f2 s = (a0 + a1) + (a2 + a3);
    return s.x + s.y;
}

// Probability-domain recurrence. State w is a scaled prob vector; per-step
// critical path: ds_write w -> 16 ds_read_b128 -> 32 pk_fma -> 1 v_mul.
// log2/exp2/anchor/output-store all run in the latency shadow.
// blocks 0..B-1: forward (log2-f into f_out); blocks B..2B-1: backward (log2-b into b_out).
__global__ void __launch_bounds__(64, 1)
hmm_recur(const float* __restrict__ obvs,
          const float* __restrict__ log_init,
          const float* __restrict__ transfer,
          const float* __restrict__ means,
          const float* __restrict__ log_stds,
          float* __restrict__ f_out,
          float* __restrict__ b_out)
{
    __shared__ float4 wbuf4[16];
    __shared__ float obs_lds[HMM_T + 4];   // +4 pad: prefetch may read index T (unused)
    const int lane = threadIdx.x;
    const int blk  = blockIdx.x;
    const bool fwd = (blk < HMM_B);
    const int b    = fwd ? blk : blk - HMM_B;

    const float mean_k   = means[lane];
    const float ls       = log_stds[lane];
    const float inv_std2 = __expf(-ls) * HALF_INV_LN2_SQRTF; // e2 = -((x-m)*is2)^2 + ce2 (log2 units)
    const float ce2      = (-ls - NEG_HALF_LOG_2PI) * INV_LN2F;
    const float li2      = log_init[lane] * INV_LN2F;

    f2 areg[32];
    const f2* Arow = (const f2*)(transfer + lane * HMM_K);
    #pragma unroll
    for (int j = 0; j < 32; ++j) areg[j] = Arow[j];

    const float* __restrict__ orow = obvs + (size_t)b * HMM_T;
    {
        const float4* o4 = (const float4*)orow;
        float4* l4 = (float4*)obs_lds;
        #pragma unroll 4
        for (int i = lane; i < HMM_T / 4; i += 64) l4[i] = o4[i];
    }
    __syncthreads();   // one-time (single wave -> waitcnt only)

    float* wbs = ((float*)wbuf4) + lane;

    if (fwd) {
        // t = 0: v0 = e2[0] + li2 (exact); w = exp2(v0)
        float x0 = obs_lds[0];
        float z0 = (x0 - mean_k) * inv_std2;
        float v0 = fmaf(-z0, z0, ce2) + li2;
        float* po = f_out + (size_t)b * HMM_T * HMM_K + lane;
        *po = v0;
        float w = exp2_fast(v0);
        float anchor = wave_max_uniform(v0);
        // dk for step t=1
        float x1 = obs_lds[1];
        float z1 = (x1 - mean_k) * inv_std2;
        float dk = exp2_fast(fmaf(-z1, z1, ce2) - anchor);
        for (int t = 1; t < HMM_T; ++t) {
            *wbs = w;                              // ds_write_b32 (chain)
            __builtin_amdgcn_wave_barrier();
            float u = matvec_row(areg, wbuf4);     // 16 ds_read_b128 + 32 pk_fma (chain)
            __builtin_amdgcn_wave_barrier();
            float wn = u * dk;                     // chain end: w_t
            // ---- shadow ----
            float v = log2_fast(wn);               // f[t] (uniform offset, cancels)
            po += HMM_K;
            *po = v;
            float an = wave_max_uniform(v);
            float xn = obs_lds[t + 1];
            float zn = (xn - mean_k) * inv_std2;
            dk = exp2_fast(fmaf(-zn, zn, ce2) - an);  // dk for step t+1
            w = wn;
        }
    } else {
        // t = T-1: b = li2
        float* po = b_out + ((size_t)b * HMM_T + (HMM_T - 1)) * HMM_K + lane;
        *po = li2;
        float w = exp2_fast(li2);
        float anchor = wave_max_uniform(li2);
        float xT = obs_lds[HMM_T - 1];
        float zT = (xT - mean_k) * inv_std2;
        float dk = exp2_fast(fmaf(-zT, zT, ce2) - anchor);  // for step t=T-1
        for (int t = HMM_T - 1; t >= 1; --t) {
            float y = w * dk;                      // (b_t (.) d_t), rescaled (chain)
            *wbs = y;
            __builtin_amdgcn_wave_barrier();
            float u = matvec_row(areg, wbuf4);     // A * y = b_{t-1} (chain)
            __builtin_amdgcn_wave_barrier();
            // ---- shadow ----
            float v = log2_fast(u);                // b[t-1]
            po -= HMM_K;
            *po = v;
            float an = wave_max_uniform(v);
            float xn = obs_lds[t - 1];
            float zn = (xn - mean_k) * inv_std2;
            dk = exp2_fast(fmaf(-zn, zn, ce2) - an);  // for step t-1
            w = u;
        }
    }
}

// gamma = ln2 * (g2 - m - log2(sum exp2(g2 - m))), g2 = f2+b2 (log2-domain, offsets cancel)
__global__ void __launch_bounds__(256)
hmm_combine(const float* __restrict__ fbuf,
            const float* __restrict__ bbuf,
            float* __restrict__ out)
{
    const size_t row = (size_t)blockIdx.x * 4 + (threadIdx.x >> 6);
    const int lane = threadIdx.x & 63;
    const size_t idx = row * HMM_K + lane;
    float g = fbuf[idx] + bbuf[idx];
    float m = g;
    #pragma unroll
    for (int off = 32; off > 0; off >>= 1) m = fmaxf(m, __shfl_xor(m, off));
    float e = exp2_fast(g - m);
    float s = e;
    #pragma unroll
    for (int off = 32; off > 0; off >>= 1) s += __shfl_xor(s, off);
    out[idx] = LN2F * ((g - m) - log2_fast(s));
}

// Fallback (ws too small): log-domain bwd fused with combine, in-place on d_out.
__global__ void __launch_bounds__(64, 1)
hmm_bwd_combine(const float* __restrict__ obvs,
                const float* __restrict__ log_init,
                const float* __restrict__ transfer,
                const float* __restrict__ means,
                const float* __restrict__ log_stds,
                float* __restrict__ fout)
{
    __shared__ float4 wbuf4[16];
    __shared__ float obs_lds[HMM_T + 4];
    const int lane = threadIdx.x;
    const int b = blockIdx.x;
    const float mean_k   = means[lane];
    const float ls       = log_stds[lane];
    const float inv_std2 = __expf(-ls) * HALF_INV_LN2_SQRTF;
    const float ce2      = (-ls - NEG_HALF_LOG_2PI) * INV_LN2F;
    const float li2      = log_init[lane] * INV_LN2F;
    f2 areg[32];
    const f2* Arow = (const f2*)(transfer + lane * HMM_K);
    #pragma unroll
    for (int j = 0; j < 32; ++j) areg[j] = Arow[j];
    const float* __restrict__ orow = obvs + (size_t)b * HMM_T;
    {
        const float4* o4 = (const float4*)orow;
        float4* l4 = (float4*)obs_lds;
        #pragma unroll 4
        for (int i = lane; i < HMM_T / 4; i += 64) l4[i] = o4[i];
    }
    __syncthreads();
    float* wbs = ((float*)wbuf4) + lane;

    float bb = li2;
    for (int t = HMM_T - 1; t >= 0; --t) {
        const size_t base = ((size_t)b * HMM_T + t) * HMM_K;
        float g = fout[base + lane] + bb;
        float m = g;
        #pragma unroll
        for (int off = 32; off > 0; off >>= 1) m = fmaxf(m, __shfl_xor(m, off));
        float e = exp2_fast(g - m);
        float s = e;
        #pragma unroll
        for (int off = 32; off > 0; off >>= 1) s += __shfl_xor(s, off);
        fout[base + lane] = LN2F * ((g - m) - log2_fast(s));
        if (t > 0) {
            float xt = obs_lds[t];
            float zt = (xt - mean_k) * inv_std2;
            float tmp = bb + fmaf(-zt, zt, ce2);
            float shift = bcast0(tmp);
            float d = fminf(tmp - shift, 100.0f);
            float wv = exp2_fast(d);
            *wbs = wv;
            __builtin_amdgcn_wave_barrier();
            float u = matvec_row(areg, wbuf4);
            __builtin_amdgcn_wave_barrier();
            bb = log2_fast(u);
        }
    }
}

extern "C" void kernel_launch(void* const* d_in, const int* in_sizes, int n_in,
                              void* d_out, int out_size, void* d_ws, size_t ws_size,
                              hipStream_t stream)
{
    const float* obvs     = (const float*)d_in[0];
    const float* log_init = (const float*)d_in[1];
    const float* transfer = (const float*)d_in[2];
    const float* means    = (const float*)d_in[3];
    const float* log_stds = (const float*)d_in[4];
    float* out = (float*)d_out;

    const size_t need = (size_t)HMM_B * HMM_T * HMM_K * sizeof(float);
    if (ws_size >= need) {
        float* bws = (float*)d_ws;
        hipLaunchKernelGGL(hmm_recur, dim3(2 * HMM_B), dim3(HMM_K), 0, stream,
                           obvs, log_init, transfer, means, log_stds, out, bws);
        hipLaunchKernelGGL(hmm_combine, dim3(HMM_B * HMM_T / 4), dim3(256), 0, stream,
                           out, bws, out);
    } else {
        hipLaunchKernelGGL(hmm_recur, dim3(HMM_B), dim3(HMM_K), 0, stream,
                           obvs, log_init, transfer, means, log_stds, out, out);
        hipLaunchKernelGGL(hmm_bwd_combine, dim3(HMM_B), dim3(HMM_K), 0, stream,
                           obvs, log_init, transfer, means, log_stds, out);
    }
}